// Round 1
// baseline (1154.739 us; speedup 1.0000x reference)
//
#include <hip/hip_runtime.h>

#define DIM 64

// ---------------------------------------------------------------------------
// deg[col[e]] += 1  (float atomic; deg buffer pre-zeroed)
// ---------------------------------------------------------------------------
__global__ void deg_kernel(const int* __restrict__ col, float* __restrict__ deg,
                           int E) {
    int e = blockIdx.x * blockDim.x + threadIdx.x;
    if (e < E) atomicAdd(&deg[col[e]], 1.0f);
}

// deg -> deg^{-1/2} in place (0 if deg == 0)
__global__ void dis_kernel(float* __restrict__ deg, int N) {
    int i = blockIdx.x * blockDim.x + threadIdx.x;
    if (i < N) {
        float d = deg[i];
        deg[i] = (d > 0.0f) ? rsqrtf(d) : 0.0f;
    }
}

// norm[e] = dis[row[e]] * dis[col[e]]
__global__ void norm_kernel(const int* __restrict__ row,
                            const int* __restrict__ col,
                            const float* __restrict__ dis,
                            float* __restrict__ nrm, int E) {
    int e = blockIdx.x * blockDim.x + threadIdx.x;
    if (e < E) nrm[e] = dis[row[e]] * dis[col[e]];
}

// ---------------------------------------------------------------------------
// SpMM scatter: y[col[e], :] += norm[e] * x[row[e], :]
// one wave per edge, lane = dim (64 lanes == 64 dims)
// ---------------------------------------------------------------------------
__global__ void spmm_kernel(const int* __restrict__ row,
                            const int* __restrict__ col,
                            const float* __restrict__ nrm,
                            const float* __restrict__ x,
                            float* __restrict__ y, int E) {
    int e = blockIdx.x * (blockDim.x >> 6) + (threadIdx.x >> 6);
    int lane = threadIdx.x & 63;
    if (e >= E) return;
    int r = row[e];
    int c = col[e];
    float w = nrm[e];
    float v = w * x[(size_t)r * DIM + lane];
    atomicAdd(&y[(size_t)c * DIM + lane], v);
}

// acc = src  (vectorized copy)
__global__ void copy4_kernel(const float4* __restrict__ src,
                             float4* __restrict__ dst, size_t n4) {
    size_t i = (size_t)blockIdx.x * blockDim.x + threadIdx.x;
    size_t stride = (size_t)gridDim.x * blockDim.x;
    for (; i < n4; i += stride) dst[i] = src[i];
}

// acc += src  (vectorized)
__global__ void add4_kernel(const float4* __restrict__ src,
                            float4* __restrict__ dst, size_t n4) {
    size_t i = (size_t)blockIdx.x * blockDim.x + threadIdx.x;
    size_t stride = (size_t)gridDim.x * blockDim.x;
    for (; i < n4; i += stride) {
        float4 a = dst[i];
        float4 b = src[i];
        a.x += b.x; a.y += b.y; a.z += b.z; a.w += b.w;
        dst[i] = a;
    }
}

// ---------------------------------------------------------------------------
// logits[p] = alpha^2 * dot(acc[u], acc[i]) ; one wave per pair
// ---------------------------------------------------------------------------
__global__ void score_kernel(const int* __restrict__ batch,
                             const float* __restrict__ acc,
                             float* __restrict__ out, int P) {
    int p = blockIdx.x * (blockDim.x >> 6) + (threadIdx.x >> 6);
    int lane = threadIdx.x & 63;
    if (p >= P) return;
    int u = batch[(size_t)p * 3 + 0];
    int it = batch[(size_t)p * 3 + 1];
    float s = acc[(size_t)u * DIM + lane] * acc[(size_t)it * DIM + lane];
    // full 64-lane butterfly reduction
    #pragma unroll
    for (int off = 32; off > 0; off >>= 1) s += __shfl_xor(s, off, 64);
    if (lane == 0) out[p] = s * 0.0625f;  // alpha^2, alpha = 1/(K+1) = 0.25
}

extern "C" void kernel_launch(void* const* d_in, const int* in_sizes, int n_in,
                              void* d_out, int out_size, void* d_ws,
                              size_t ws_size, hipStream_t stream) {
    const float* emb = (const float*)d_in[0];
    const int* edge_index = (const int*)d_in[1];
    const int* batch = (const int*)d_in[2];
    float* out = (float*)d_out;

    const int N = in_sizes[0] / DIM;   // 200000
    const int E = in_sizes[1] / 2;     // 1250000
    const int P = out_size;            // 4096 * 101

    const int* row = edge_index;       // sources
    const int* col = edge_index + E;   // targets

    const size_t ND = (size_t)N * DIM;

    // workspace layout (~160 MB)
    char* ws = (char*)d_ws;
    float* acc = (float*)ws; ws += ND * sizeof(float);
    float* xa  = (float*)ws; ws += ND * sizeof(float);
    float* xb  = (float*)ws; ws += ND * sizeof(float);
    float* dis = (float*)ws; ws += (size_t)N * sizeof(float);
    float* nrm = (float*)ws;

    // --- degree / normalization coefficients ---
    hipMemsetAsync(dis, 0, (size_t)N * sizeof(float), stream);
    deg_kernel<<<(E + 255) / 256, 256, 0, stream>>>(col, dis, E);
    dis_kernel<<<(N + 255) / 256, 256, 0, stream>>>(dis, N);
    norm_kernel<<<(E + 255) / 256, 256, 0, stream>>>(row, col, dis, nrm, E);

    const size_t n4 = ND / 4;
    const int eltBlocks = 2048;  // grid-stride, saturates 256 CUs

    // acc = emb (layer-0 term; alpha applied at scoring)
    copy4_kernel<<<eltBlocks, 256, 0, stream>>>((const float4*)emb,
                                                (float4*)acc, n4);

    const int spmmBlocks = (E + 3) / 4;  // 4 waves (edges) per 256-thread block

    // layer 1: emb -> xa
    hipMemsetAsync(xa, 0, ND * sizeof(float), stream);
    spmm_kernel<<<spmmBlocks, 256, 0, stream>>>(row, col, nrm, emb, xa, E);
    add4_kernel<<<eltBlocks, 256, 0, stream>>>((const float4*)xa, (float4*)acc, n4);

    // layer 2: xa -> xb
    hipMemsetAsync(xb, 0, ND * sizeof(float), stream);
    spmm_kernel<<<spmmBlocks, 256, 0, stream>>>(row, col, nrm, xa, xb, E);
    add4_kernel<<<eltBlocks, 256, 0, stream>>>((const float4*)xb, (float4*)acc, n4);

    // layer 3: xb -> xa (reuse)
    hipMemsetAsync(xa, 0, ND * sizeof(float), stream);
    spmm_kernel<<<spmmBlocks, 256, 0, stream>>>(row, col, nrm, xb, xa, E);
    add4_kernel<<<eltBlocks, 256, 0, stream>>>((const float4*)xa, (float4*)acc, n4);

    // --- scoring ---
    score_kernel<<<(P + 3) / 4, 256, 0, stream>>>(batch, acc, out, P);
}

// Round 2
// 628.736 us; speedup vs baseline: 1.8366x; 1.8366x over previous
//
#include <hip/hip_runtime.h>

#define DIM 64
#define SCAN_ELEMS 1024  // elements per scan block (256 threads x 4)

// ---------------------------------------------------------------------------
// histogram of destinations: cnt[col[e]] += 1  (int atomics; cnt pre-zeroed)
// ---------------------------------------------------------------------------
__global__ void hist_kernel(const int* __restrict__ col, int* __restrict__ cnt,
                            int E) {
    int e = blockIdx.x * blockDim.x + threadIdx.x;
    if (e < E) atomicAdd(&cnt[col[e]], 1);
}

// dis[i] = cnt[i] > 0 ? rsqrt(cnt[i]) : 0
__global__ void dis_kernel(const int* __restrict__ cnt, float* __restrict__ dis,
                           int N) {
    int i = blockIdx.x * blockDim.x + threadIdx.x;
    if (i < N) {
        int c = cnt[i];
        dis[i] = (c > 0) ? rsqrtf((float)c) : 0.0f;
    }
}

// per-block (1024-elem) sums of cnt -> sums[b]
__global__ void block_sum_kernel(const int* __restrict__ cnt,
                                 int* __restrict__ sums, int N) {
    int tid = threadIdx.x;
    int base = blockIdx.x * SCAN_ELEMS + tid * 4;
    int s = 0;
    #pragma unroll
    for (int k = 0; k < 4; k++) {
        int idx = base + k;
        if (idx < N) s += cnt[idx];
    }
    __shared__ int lds[256];
    lds[tid] = s;
    __syncthreads();
    for (int off = 128; off > 0; off >>= 1) {
        if (tid < off) lds[tid] += lds[tid + off];
        __syncthreads();
    }
    if (tid == 0) sums[blockIdx.x] = lds[0];
}

// single-block exclusive scan of sums[0..nb)  (nb <= 256)
__global__ void scan_sums_kernel(int* __restrict__ sums, int nb) {
    __shared__ int lds[256];
    int tid = threadIdx.x;
    int v = (tid < nb) ? sums[tid] : 0;
    lds[tid] = v;
    __syncthreads();
    for (int off = 1; off < 256; off <<= 1) {
        int t = (tid >= off) ? lds[tid - off] : 0;
        __syncthreads();
        lds[tid] += t;
        __syncthreads();
    }
    if (tid < nb) sums[tid] = lds[tid] - v;  // exclusive
}

// row_ptr[i] = global exclusive prefix of cnt; row_ptr[N] = E
__global__ void rowptr_kernel(const int* __restrict__ cnt,
                              const int* __restrict__ sums,
                              int* __restrict__ row_ptr, int N, int E) {
    int tid = threadIdx.x;
    int base = blockIdx.x * SCAN_ELEMS + tid * 4;
    int c[4];
    int local = 0;
    #pragma unroll
    for (int k = 0; k < 4; k++) {
        int idx = base + k;
        c[k] = (idx < N) ? cnt[idx] : 0;
        local += c[k];
    }
    __shared__ int lds[256];
    lds[tid] = local;
    __syncthreads();
    for (int off = 1; off < 256; off <<= 1) {
        int t = (tid >= off) ? lds[tid - off] : 0;
        __syncthreads();
        lds[tid] += t;
        __syncthreads();
    }
    int excl = lds[tid] - local + sums[blockIdx.x];
    #pragma unroll
    for (int k = 0; k < 4; k++) {
        int idx = base + k;
        if (idx < N) row_ptr[idx] = excl;
        excl += c[k];
    }
    if (blockIdx.x == 0 && tid == 0) row_ptr[N] = E;
}

// cursor[i] = row_ptr[i]
__global__ void cursor_init_kernel(const int* __restrict__ row_ptr,
                                   int* __restrict__ cursor, int N) {
    int i = blockIdx.x * blockDim.x + threadIdx.x;
    if (i < N) cursor[i] = row_ptr[i];
}

// csr_src[pos] = row[e] bucketed by destination
__global__ void fill_kernel(const int* __restrict__ row,
                            const int* __restrict__ col,
                            int* __restrict__ cursor,
                            int* __restrict__ csr_src, int E) {
    int e = blockIdx.x * blockDim.x + threadIdx.x;
    if (e < E) {
        int pos = atomicAdd(&cursor[col[e]], 1);
        csr_src[pos] = row[e];
    }
}

// acc = src
__global__ void copy4_kernel(const float4* __restrict__ src,
                             float4* __restrict__ dst, size_t n4) {
    size_t i = (size_t)blockIdx.x * blockDim.x + threadIdx.x;
    size_t stride = (size_t)gridDim.x * blockDim.x;
    for (; i < n4; i += stride) dst[i] = src[i];
}

// ---------------------------------------------------------------------------
// pull SpMM, fused accumulate:
//   y[i,:] = dis[i] * sum_{e in csr[i]} dis[src_e] * x[src_e,:]
//   acc[i,:] += y[i,:]
// one wave per destination node, lane = dim
// ---------------------------------------------------------------------------
__global__ void spmm_pull_kernel(const int* __restrict__ row_ptr,
                                 const int* __restrict__ csr_src,
                                 const float* __restrict__ dis,
                                 const float* __restrict__ x,
                                 float* __restrict__ y,
                                 float* __restrict__ acc, int N) {
    int i = blockIdx.x * (blockDim.x >> 6) + (threadIdx.x >> 6);
    int lane = threadIdx.x & 63;
    if (i >= N) return;
    int b = row_ptr[i];
    int e = row_ptr[i + 1];
    float s = 0.0f;
    int j = b;
    for (; j + 1 < e; j += 2) {  // 2-way unroll: 2 gathers in flight
        int s0 = csr_src[j];
        int s1 = csr_src[j + 1];
        float w0 = dis[s0];
        float w1 = dis[s1];
        float v0 = x[(size_t)s0 * DIM + lane];
        float v1 = x[(size_t)s1 * DIM + lane];
        s += w0 * v0 + w1 * v1;
    }
    if (j < e) {
        int s0 = csr_src[j];
        s += dis[s0] * x[(size_t)s0 * DIM + lane];
    }
    s *= dis[i];  // common factor dis[dst]
    size_t o = (size_t)i * DIM + lane;
    y[o] = s;
    acc[o] += s;
}

// ---------------------------------------------------------------------------
// logits[p] = alpha^2 * dot(acc[u], acc[i]) ; one wave per pair
// ---------------------------------------------------------------------------
__global__ void score_kernel(const int* __restrict__ batch,
                             const float* __restrict__ acc,
                             float* __restrict__ out, int P) {
    int p = blockIdx.x * (blockDim.x >> 6) + (threadIdx.x >> 6);
    int lane = threadIdx.x & 63;
    if (p >= P) return;
    int u = batch[(size_t)p * 3 + 0];
    int it = batch[(size_t)p * 3 + 1];
    float s = acc[(size_t)u * DIM + lane] * acc[(size_t)it * DIM + lane];
    #pragma unroll
    for (int off = 32; off > 0; off >>= 1) s += __shfl_xor(s, off, 64);
    if (lane == 0) out[p] = s * 0.0625f;  // alpha^2, alpha = 1/(K_LAYERS+1)
}

extern "C" void kernel_launch(void* const* d_in, const int* in_sizes, int n_in,
                              void* d_out, int out_size, void* d_ws,
                              size_t ws_size, hipStream_t stream) {
    const float* emb = (const float*)d_in[0];
    const int* edge_index = (const int*)d_in[1];
    const int* batch = (const int*)d_in[2];
    float* out = (float*)d_out;

    const int N = in_sizes[0] / DIM;   // 200000
    const int E = in_sizes[1] / 2;     // 1250000
    const int P = out_size;            // 4096 * 101

    const int* row = edge_index;       // sources
    const int* col = edge_index + E;   // targets

    const size_t ND = (size_t)N * DIM;
    const int nScanBlocks = (N + SCAN_ELEMS - 1) / SCAN_ELEMS;  // 196

    // workspace layout (~161 MB)
    char* ws = (char*)d_ws;
    float* acc     = (float*)ws; ws += ND * sizeof(float);
    float* xa      = (float*)ws; ws += ND * sizeof(float);
    float* xb      = (float*)ws; ws += ND * sizeof(float);
    float* dis     = (float*)ws; ws += (size_t)N * sizeof(float);
    int*   cnt     = (int*)ws;   ws += (size_t)N * sizeof(int);
    int*   row_ptr = (int*)ws;   ws += (size_t)(N + 1) * sizeof(int);
    int*   cursor  = (int*)ws;   ws += (size_t)N * sizeof(int);
    int*   sums    = (int*)ws;   ws += (size_t)nScanBlocks * sizeof(int);
    int*   csr_src = (int*)ws;

    // --- CSR build: histogram -> dis -> scan -> fill ---
    hipMemsetAsync(cnt, 0, (size_t)N * sizeof(int), stream);
    hist_kernel<<<(E + 255) / 256, 256, 0, stream>>>(col, cnt, E);
    dis_kernel<<<(N + 255) / 256, 256, 0, stream>>>(cnt, dis, N);
    block_sum_kernel<<<nScanBlocks, 256, 0, stream>>>(cnt, sums, N);
    scan_sums_kernel<<<1, 256, 0, stream>>>(sums, nScanBlocks);
    rowptr_kernel<<<nScanBlocks, 256, 0, stream>>>(cnt, sums, row_ptr, N, E);
    cursor_init_kernel<<<(N + 255) / 256, 256, 0, stream>>>(row_ptr, cursor, N);
    fill_kernel<<<(E + 255) / 256, 256, 0, stream>>>(row, col, cursor, csr_src, E);

    // acc = emb (layer-0 term; alpha applied at scoring)
    const size_t n4 = ND / 4;
    copy4_kernel<<<2048, 256, 0, stream>>>((const float4*)emb, (float4*)acc, n4);

    // --- 3 pull-SpMM layers, acc fused ---
    const int spmmBlocks = (N + 3) / 4;  // 4 waves (nodes) per 256-thread block
    spmm_pull_kernel<<<spmmBlocks, 256, 0, stream>>>(row_ptr, csr_src, dis, emb, xa, acc, N);
    spmm_pull_kernel<<<spmmBlocks, 256, 0, stream>>>(row_ptr, csr_src, dis, xa, xb, acc, N);
    spmm_pull_kernel<<<spmmBlocks, 256, 0, stream>>>(row_ptr, csr_src, dis, xb, xa, acc, N);

    // --- scoring ---
    score_kernel<<<(P + 3) / 4, 256, 0, stream>>>(batch, acc, out, P);
}

// Round 3
// 468.071 us; speedup vs baseline: 2.4670x; 1.3433x over previous
//
#include <hip/hip_runtime.h>

#define DIM 64
#define SCAN_ELEMS 1024  // elements per scan block (256 threads x 4)

// ---------------------------------------------------------------------------
// histogram of destinations: cnt[col[e]] += 1  (int atomics; cnt pre-zeroed)
// ---------------------------------------------------------------------------
__global__ void hist_kernel(const int* __restrict__ col, int* __restrict__ cnt,
                            int E) {
    int e = blockIdx.x * blockDim.x + threadIdx.x;
    if (e < E) atomicAdd(&cnt[col[e]], 1);
}

// per-block (1024-elem) sums of cnt -> sums[b]
__global__ void block_sum_kernel(const int* __restrict__ cnt,
                                 int* __restrict__ sums, int N) {
    int tid = threadIdx.x;
    int base = blockIdx.x * SCAN_ELEMS + tid * 4;
    int s = 0;
    #pragma unroll
    for (int k = 0; k < 4; k++) {
        int idx = base + k;
        if (idx < N) s += cnt[idx];
    }
    __shared__ int lds[256];
    lds[tid] = s;
    __syncthreads();
    for (int off = 128; off > 0; off >>= 1) {
        if (tid < off) lds[tid] += lds[tid + off];
        __syncthreads();
    }
    if (tid == 0) sums[blockIdx.x] = lds[0];
}

// single-block exclusive scan of sums[0..nb)  (nb <= 256)
__global__ void scan_sums_kernel(int* __restrict__ sums, int nb) {
    __shared__ int lds[256];
    int tid = threadIdx.x;
    int v = (tid < nb) ? sums[tid] : 0;
    lds[tid] = v;
    __syncthreads();
    for (int off = 1; off < 256; off <<= 1) {
        int t = (tid >= off) ? lds[tid - off] : 0;
        __syncthreads();
        lds[tid] += t;
        __syncthreads();
    }
    if (tid < nb) sums[tid] = lds[tid] - v;  // exclusive
}

// row_ptr[i] = global exclusive prefix of cnt; row_ptr[N] = E
__global__ void rowptr_kernel(const int* __restrict__ cnt,
                              const int* __restrict__ sums,
                              int* __restrict__ row_ptr, int N, int E) {
    int tid = threadIdx.x;
    int base = blockIdx.x * SCAN_ELEMS + tid * 4;
    int c[4];
    int local = 0;
    #pragma unroll
    for (int k = 0; k < 4; k++) {
        int idx = base + k;
        c[k] = (idx < N) ? cnt[idx] : 0;
        local += c[k];
    }
    __shared__ int lds[256];
    lds[tid] = local;
    __syncthreads();
    for (int off = 1; off < 256; off <<= 1) {
        int t = (tid >= off) ? lds[tid - off] : 0;
        __syncthreads();
        lds[tid] += t;
        __syncthreads();
    }
    int excl = lds[tid] - local + sums[blockIdx.x];
    #pragma unroll
    for (int k = 0; k < 4; k++) {
        int idx = base + k;
        if (idx < N) row_ptr[idx] = excl;
        excl += c[k];
    }
    if (blockIdx.x == 0 && tid == 0) row_ptr[N] = E;
}

// cursor[i] = row_ptr[i]
__global__ void cursor_init_kernel(const int* __restrict__ row_ptr,
                                   int* __restrict__ cursor, int N) {
    int i = blockIdx.x * blockDim.x + threadIdx.x;
    if (i < N) cursor[i] = row_ptr[i];
}

// csr_src[pos] = row[e] bucketed by destination
__global__ void fill_kernel(const int* __restrict__ row,
                            const int* __restrict__ col,
                            int* __restrict__ cursor,
                            int* __restrict__ csr_src, int E) {
    int e = blockIdx.x * blockDim.x + threadIdx.x;
    if (e < E) {
        int pos = atomicAdd(&cursor[col[e]], 1);
        csr_src[pos] = row[e];
    }
}

// ---------------------------------------------------------------------------
// prescale: acc = emb ; z0 = dis * emb   (16-lane group per node, float4 lane)
// ---------------------------------------------------------------------------
__global__ void prescale_kernel(const float4* __restrict__ emb4,
                                const int* __restrict__ cnt,
                                float4* __restrict__ acc4,
                                float4* __restrict__ z4, int N) {
    int i = (blockIdx.x * blockDim.x + threadIdx.x) >> 4;
    int gl = threadIdx.x & 15;
    if (i >= N) return;
    int c = cnt[i];
    float wd = (c > 0) ? rsqrtf((float)c) : 0.0f;
    size_t o = (size_t)i * 16 + gl;
    float4 v = emb4[o];
    acc4[o] = v;
    float4 z = {v.x * wd, v.y * wd, v.z * wd, v.w * wd};
    z4[o] = z;
}

// ---------------------------------------------------------------------------
// pull SpMM on pre-scaled z:   t_i = sum_{e in csr[i]} z[src_e]
//   acc[i] += wd * t          (wd = rsqrt(rowlen))
//   z_next[i] = wd*wd * t     (skipped when write_z == 0, last layer)
// 16-lane group per dst node (lane = float4 of the row); 4-way edge unroll
// ---------------------------------------------------------------------------
__global__ void spmm_pull_kernel(const int* __restrict__ row_ptr,
                                 const int* __restrict__ csr_src,
                                 const float4* __restrict__ z4,
                                 float4* __restrict__ znext4,
                                 float4* __restrict__ acc4, int N,
                                 int write_z) {
    int i = (blockIdx.x * blockDim.x + threadIdx.x) >> 4;
    int gl = threadIdx.x & 15;
    if (i >= N) return;
    int b = row_ptr[i];
    int e = row_ptr[i + 1];
    float4 sa = {0, 0, 0, 0}, sb = sa, sc = sa, sd = sa;
    int j = b;
    for (; j + 3 < e; j += 4) {  // 4 independent gathers in flight
        int i0 = csr_src[j], i1 = csr_src[j + 1];
        int i2 = csr_src[j + 2], i3 = csr_src[j + 3];
        float4 v0 = z4[(size_t)i0 * 16 + gl];
        float4 v1 = z4[(size_t)i1 * 16 + gl];
        float4 v2 = z4[(size_t)i2 * 16 + gl];
        float4 v3 = z4[(size_t)i3 * 16 + gl];
        sa.x += v0.x; sa.y += v0.y; sa.z += v0.z; sa.w += v0.w;
        sb.x += v1.x; sb.y += v1.y; sb.z += v1.z; sb.w += v1.w;
        sc.x += v2.x; sc.y += v2.y; sc.z += v2.z; sc.w += v2.w;
        sd.x += v3.x; sd.y += v3.y; sd.z += v3.z; sd.w += v3.w;
    }
    for (; j < e; ++j) {
        float4 v = z4[(size_t)csr_src[j] * 16 + gl];
        sa.x += v.x; sa.y += v.y; sa.z += v.z; sa.w += v.w;
    }
    float4 t;
    t.x = (sa.x + sb.x) + (sc.x + sd.x);
    t.y = (sa.y + sb.y) + (sc.y + sd.y);
    t.z = (sa.z + sb.z) + (sc.z + sd.z);
    t.w = (sa.w + sb.w) + (sc.w + sd.w);
    int deg = e - b;  // row length == in-degree
    float wd = (deg > 0) ? rsqrtf((float)deg) : 0.0f;
    size_t o = (size_t)i * 16 + gl;
    float4 a = acc4[o];
    a.x += wd * t.x; a.y += wd * t.y; a.z += wd * t.z; a.w += wd * t.w;
    acc4[o] = a;
    if (write_z) {
        float w2 = wd * wd;
        float4 z = {w2 * t.x, w2 * t.y, w2 * t.z, w2 * t.w};
        znext4[o] = z;
    }
}

// ---------------------------------------------------------------------------
// logits[p] = alpha^2 * dot(acc[u], acc[i]) ; 16-lane group per pair
// ---------------------------------------------------------------------------
__global__ void score_kernel(const int* __restrict__ batch,
                             const float4* __restrict__ acc4,
                             float* __restrict__ out, int P) {
    int p = (blockIdx.x * blockDim.x + threadIdx.x) >> 4;
    int gl = threadIdx.x & 15;
    if (p >= P) return;
    int u = batch[(size_t)p * 3 + 0];
    int it = batch[(size_t)p * 3 + 1];
    float4 a = acc4[(size_t)u * 16 + gl];
    float4 b = acc4[(size_t)it * 16 + gl];
    float s = a.x * b.x + a.y * b.y + a.z * b.z + a.w * b.w;
    s += __shfl_xor(s, 8, 64);  // xor masks < 16 stay within the group
    s += __shfl_xor(s, 4, 64);
    s += __shfl_xor(s, 2, 64);
    s += __shfl_xor(s, 1, 64);
    if (gl == 0) out[p] = s * 0.0625f;  // alpha^2, alpha = 1/(K_LAYERS+1)
}

extern "C" void kernel_launch(void* const* d_in, const int* in_sizes, int n_in,
                              void* d_out, int out_size, void* d_ws,
                              size_t ws_size, hipStream_t stream) {
    const float* emb = (const float*)d_in[0];
    const int* edge_index = (const int*)d_in[1];
    const int* batch = (const int*)d_in[2];
    float* out = (float*)d_out;

    const int N = in_sizes[0] / DIM;   // 200000
    const int E = in_sizes[1] / 2;     // 1250000
    const int P = out_size;            // 4096 * 101

    const int* row = edge_index;       // sources
    const int* col = edge_index + E;   // targets

    const size_t ND = (size_t)N * DIM;
    const int nScanBlocks = (N + SCAN_ELEMS - 1) / SCAN_ELEMS;  // 196

    // workspace layout (~160 MB)
    char* ws = (char*)d_ws;
    float* acc     = (float*)ws; ws += ND * sizeof(float);
    float* za      = (float*)ws; ws += ND * sizeof(float);
    float* zb      = (float*)ws; ws += ND * sizeof(float);
    int*   cnt     = (int*)ws;   ws += (size_t)N * sizeof(int);
    int*   row_ptr = (int*)ws;   ws += (size_t)(N + 1) * sizeof(int);
    int*   cursor  = (int*)ws;   ws += (size_t)N * sizeof(int);
    int*   sums    = (int*)ws;   ws += (size_t)nScanBlocks * sizeof(int);
    int*   csr_src = (int*)ws;

    // --- CSR build: histogram -> scan -> fill ---
    hipMemsetAsync(cnt, 0, (size_t)N * sizeof(int), stream);
    hist_kernel<<<(E + 255) / 256, 256, 0, stream>>>(col, cnt, E);
    block_sum_kernel<<<nScanBlocks, 256, 0, stream>>>(cnt, sums, N);
    scan_sums_kernel<<<1, 256, 0, stream>>>(sums, nScanBlocks);
    rowptr_kernel<<<nScanBlocks, 256, 0, stream>>>(cnt, sums, row_ptr, N, E);
    cursor_init_kernel<<<(N + 255) / 256, 256, 0, stream>>>(row_ptr, cursor, N);
    fill_kernel<<<(E + 255) / 256, 256, 0, stream>>>(row, col, cursor, csr_src, E);

    // acc = emb ; za = dis * emb
    const int nodeBlocks = (N + 15) / 16;  // 16-lane group per node
    prescale_kernel<<<nodeBlocks, 256, 0, stream>>>((const float4*)emb, cnt,
                                                    (float4*)acc, (float4*)za, N);

    // --- 3 pull-SpMM layers on scaled z, acc fused ---
    spmm_pull_kernel<<<nodeBlocks, 256, 0, stream>>>(row_ptr, csr_src,
        (const float4*)za, (float4*)zb, (float4*)acc, N, 1);
    spmm_pull_kernel<<<nodeBlocks, 256, 0, stream>>>(row_ptr, csr_src,
        (const float4*)zb, (float4*)za, (float4*)acc, N, 1);
    spmm_pull_kernel<<<nodeBlocks, 256, 0, stream>>>(row_ptr, csr_src,
        (const float4*)za, (float4*)zb, (float4*)acc, N, 0);  // last: skip z

    // --- scoring ---
    score_kernel<<<(P + 15) / 16, 256, 0, stream>>>(batch, (const float4*)acc,
                                                    out, P);
}